// Round 8
// baseline (829.866 us; speedup 1.0000x reference)
//
#include <hip/hip_runtime.h>
#include <hip/hip_bf16.h>

// GIN forward, round 8: barrier-free GEMM phases. B-fragments stream
// global->VGPR from L2-hot Wt with 1-deep explicit prefetch (no W LDS, no
// per-chunk barriers). Y still bounces through 32KB LDS (2 barriers/block).
// R7 post-mortem: W-dbuf's 64KB LDS cost a resident block (occ 25->17%) and
// lost to R5; R6 failed only because it held ALL W in regs (128) -- holding
// a 1-chunk prefetch (32 regs) is fine.

constexpr int HDIM = 256;

typedef short v8s __attribute__((ext_vector_type(8)));
typedef float v4f __attribute__((ext_vector_type(4)));

__device__ __forceinline__ float bflo(unsigned int u) { return __uint_as_float(u << 16); }
__device__ __forceinline__ float bfhi(unsigned int u) { return __uint_as_float(u & 0xffff0000u); }
__device__ __forceinline__ unsigned short f2bf(float f) {
    unsigned int u = __float_as_uint(f);
    return (unsigned short)((u + 0x7fffu + ((u >> 16) & 1u)) >> 16);  // RNE
}

// ================= CSR build =================
__global__ __launch_bounds__(256) void hist_kernel(
    const int* __restrict__ dst, int* __restrict__ deg, int n_edges)
{
    int e = blockIdx.x * 256 + threadIdx.x;
    if (e < n_edges) atomicAdd(&deg[dst[e]], 1);
}

__global__ __launch_bounds__(256) void scan1_kernel(
    const int* __restrict__ deg, int* __restrict__ scanex,
    int* __restrict__ partials, int n)
{
    __shared__ int s[256];
    int i = blockIdx.x * 256 + threadIdx.x;
    int v = (i < n) ? deg[i] : 0;
    s[threadIdx.x] = v;
    __syncthreads();
#pragma unroll
    for (int off = 1; off < 256; off <<= 1) {
        int t = (threadIdx.x >= off) ? s[threadIdx.x - off] : 0;
        __syncthreads();
        s[threadIdx.x] += t;
        __syncthreads();
    }
    if (i < n) scanex[i] = s[threadIdx.x] - v;
    if (threadIdx.x == 255) partials[blockIdx.x] = s[255];
}

__global__ __launch_bounds__(512) void scan2_kernel(int* __restrict__ partials, int nb)
{
    __shared__ int s[512];
    int v = (threadIdx.x < nb) ? partials[threadIdx.x] : 0;
    s[threadIdx.x] = v;
    __syncthreads();
#pragma unroll
    for (int off = 1; off < 512; off <<= 1) {
        int t = (threadIdx.x >= off) ? s[threadIdx.x - off] : 0;
        __syncthreads();
        s[threadIdx.x] += t;
        __syncthreads();
    }
    if (threadIdx.x < nb) partials[threadIdx.x] = s[threadIdx.x] - v;
}

__global__ __launch_bounds__(256) void scan3_kernel(
    const int* __restrict__ scanex, const int* __restrict__ partials,
    int* __restrict__ rowptr, int* __restrict__ cursor, int n, int n_edges)
{
    int i = blockIdx.x * 256 + threadIdx.x;
    if (i < n) {
        int v = scanex[i] + partials[blockIdx.x];
        rowptr[i] = v;
        cursor[i] = v;
    }
    if (i == 0) rowptr[n] = n_edges;
}

__global__ __launch_bounds__(256) void fill_kernel(
    const int* __restrict__ src, const int* __restrict__ dst,
    int* __restrict__ cursor, int* __restrict__ csr_src, int n_edges)
{
    int e = blockIdx.x * 256 + threadIdx.x;
    if (e >= n_edges) return;
    int slot = atomicAdd(&cursor[dst[e]], 1);
    csr_src[slot] = src[e];
}

// ================= weight convert: Wt[n][k] = bf16(W[k][n]) =================
__global__ __launch_bounds__(256) void convw_kernel(
    const float* __restrict__ g0w2, const float* __restrict__ gw1,
    const float* __restrict__ gw2, unsigned short* __restrict__ Bts)
{
    int gid = blockIdx.x * 256 + threadIdx.x;
    if (gid >= 9 * 65536) return;
    int m = gid >> 16;
    int e = gid & 0xffff;
    int n = e >> 8, k = e & 255;
    const float* W = (m == 0) ? g0w2
                   : (m <= 4) ? gw1 + (size_t)(m - 1) * 65536
                              : gw2 + (size_t)(m - 5) * 65536;
    Bts[(size_t)m * 65536 + n * 256 + k] = f2bf(W[k * 256 + n]);
}

// ================= aggregation (gather) =================
__global__ __launch_bounds__(256) void agg0_kernel(
    const float* __restrict__ x, const int* __restrict__ rowptr,
    const int* __restrict__ csr_src, float* __restrict__ xsum, int n)
{
    int gid = blockIdx.x * 256 + threadIdx.x;
    int node = gid >> 4, f = gid & 15;
    if (node >= n || f >= 11) return;
    float acc = x[(size_t)node * 11 + f];
    int beg = rowptr[node], end = rowptr[node + 1];
    for (int e = beg; e < end; e++)
        acc += x[(size_t)csr_src[e] * 11 + f];
    xsum[(size_t)node * 11 + f] = acc;
}

// half-wave (32 lanes x 16B) per node, neighbor loop unrolled x2 for ILP
__global__ __launch_bounds__(256) void agg_bf_kernel(
    const unsigned short* __restrict__ h, const int* __restrict__ rowptr,
    const int* __restrict__ csr_src, unsigned short* __restrict__ out, int n)
{
    int node = blockIdx.x * 8 + (threadIdx.x >> 5);
    if (node >= n) return;
    int l = threadIdx.x & 31;
    uint4 raw = *(const uint4*)&h[(size_t)node * HDIM + l * 8];
    float a0 = bflo(raw.x), a1 = bfhi(raw.x), a2 = bflo(raw.y), a3 = bfhi(raw.y);
    float a4 = bflo(raw.z), a5 = bfhi(raw.z), a6 = bflo(raw.w), a7 = bfhi(raw.w);
    int beg = rowptr[node], end = rowptr[node + 1];
    int e = beg;
    for (; e + 1 < end; e += 2) {
        int s0 = csr_src[e], s1 = csr_src[e + 1];
        uint4 r0 = *(const uint4*)&h[(size_t)s0 * HDIM + l * 8];
        uint4 r1 = *(const uint4*)&h[(size_t)s1 * HDIM + l * 8];
        a0 += bflo(r0.x); a1 += bfhi(r0.x); a2 += bflo(r0.y); a3 += bfhi(r0.y);
        a4 += bflo(r0.z); a5 += bfhi(r0.z); a6 += bflo(r0.w); a7 += bfhi(r0.w);
        a0 += bflo(r1.x); a1 += bfhi(r1.x); a2 += bflo(r1.y); a3 += bfhi(r1.y);
        a4 += bflo(r1.z); a5 += bfhi(r1.z); a6 += bflo(r1.w); a7 += bfhi(r1.w);
    }
    if (e < end) {
        int s0 = csr_src[e];
        uint4 r0 = *(const uint4*)&h[(size_t)s0 * HDIM + l * 8];
        a0 += bflo(r0.x); a1 += bfhi(r0.x); a2 += bflo(r0.y); a3 += bfhi(r0.y);
        a4 += bflo(r0.z); a5 += bfhi(r0.z); a6 += bflo(r0.w); a7 += bfhi(r0.w);
    }
    uint4 o;
    o.x = (unsigned int)f2bf(a0) | ((unsigned int)f2bf(a1) << 16);
    o.y = (unsigned int)f2bf(a2) | ((unsigned int)f2bf(a3) << 16);
    o.z = (unsigned int)f2bf(a4) | ((unsigned int)f2bf(a5) << 16);
    o.w = (unsigned int)f2bf(a6) | ((unsigned int)f2bf(a7) << 16);
    *(uint4*)&out[(size_t)node * HDIM + l * 8] = o;
}

// ================= layer-0 GEMM (K=11) =================
__global__ __launch_bounds__(256) void gemm0_kernel(
    const float* __restrict__ xsum, const float* __restrict__ w1,
    const float* __restrict__ b1, unsigned short* __restrict__ out, int M)
{
    int row = blockIdx.x * 4 + (threadIdx.x >> 6);
    if (row >= M) return;
    int lane = threadIdx.x & 63;
    float xr[11];
#pragma unroll
    for (int k = 0; k < 11; k++) xr[k] = xsum[(size_t)row * 11 + k];
    int n = lane * 4;
    float4 acc = *(const float4*)&b1[n];
#pragma unroll
    for (int k = 0; k < 11; k++) {
        float4 w = *(const float4*)&w1[k * HDIM + n];
        acc.x = fmaf(xr[k], w.x, acc.x);
        acc.y = fmaf(xr[k], w.y, acc.y);
        acc.z = fmaf(xr[k], w.z, acc.z);
        acc.w = fmaf(xr[k], w.w, acc.w);
    }
    uint2 o;
    o.x = (unsigned int)f2bf(fmaxf(acc.x, 0.f)) | ((unsigned int)f2bf(fmaxf(acc.y, 0.f)) << 16);
    o.y = (unsigned int)f2bf(fmaxf(acc.z, 0.f)) | ((unsigned int)f2bf(fmaxf(acc.w, 0.f)) << 16);
    *(uint2*)&out[(size_t)row * HDIM + n] = o;
}

// ================= barrier-free single GEMM: C = act(A @ W + bias) =========
// 64-row block, 4 waves; wave w -> cols [w*64,(w+1)*64). A and B frags both
// stream global->VGPR with 1-deep prefetch. No barriers in the K-loop.
__global__ __launch_bounds__(256, 3) void gemm_one(
    const unsigned short* __restrict__ A, const unsigned short* __restrict__ Wt,
    const float* __restrict__ bias, unsigned short* __restrict__ C,
    int M, int do_relu)
{
    __shared__ short ebuf[4 * 2304];   // 18KB per-wave epilogue bounce
    const int tid = threadIdx.x;
    const int w = tid >> 6, lane = tid & 63;
    const int q = lane >> 4, r = lane & 15;
    const int m0 = blockIdx.x * 64;

    int grow[4];
#pragma unroll
    for (int mi = 0; mi < 4; mi++) {
        int gr = m0 + mi * 16 + r; if (gr >= M) gr = M - 1;
        grow[mi] = gr;
    }

    v8s af[4], bf[4], afn[4], bfn[4];
#pragma unroll
    for (int mi = 0; mi < 4; mi++)
        af[mi] = *(const v8s*)&A[(size_t)grow[mi] * HDIM + q * 8];
#pragma unroll
    for (int ni = 0; ni < 4; ni++)
        bf[ni] = *(const v8s*)&Wt[(size_t)(w * 64 + ni * 16 + r) * HDIM + q * 8];

    v4f acc[4][4];
#pragma unroll
    for (int i = 0; i < 4; i++)
#pragma unroll
        for (int j = 0; j < 4; j++)
            acc[i][j] = (v4f){0.f, 0.f, 0.f, 0.f};

#pragma unroll
    for (int kc = 0; kc < 8; kc++) {
        if (kc < 7) {
            int ko = (kc + 1) * 32 + q * 8;
#pragma unroll
            for (int mi = 0; mi < 4; mi++)
                afn[mi] = *(const v8s*)&A[(size_t)grow[mi] * HDIM + ko];
#pragma unroll
            for (int ni = 0; ni < 4; ni++)
                bfn[ni] = *(const v8s*)&Wt[(size_t)(w * 64 + ni * 16 + r) * HDIM + ko];
        }
#pragma unroll
        for (int mi = 0; mi < 4; mi++)
#pragma unroll
            for (int ni = 0; ni < 4; ni++)
                acc[mi][ni] = __builtin_amdgcn_mfma_f32_16x16x32_bf16(
                    af[mi], bf[ni], acc[mi][ni], 0, 0, 0);
#pragma unroll
        for (int mi = 0; mi < 4; mi++) af[mi] = afn[mi];
#pragma unroll
        for (int ni = 0; ni < 4; ni++) bf[ni] = bfn[ni];
    }

    float bv[4];
#pragma unroll
    for (int ni = 0; ni < 4; ni++)
        bv[ni] = bias[w * 64 + ni * 16 + r];
#pragma unroll
    for (int mi = 0; mi < 4; mi++) {
        short* cw = &ebuf[w * 2304 + (mi & 1) * 1152];
#pragma unroll
        for (int ni = 0; ni < 4; ni++)
#pragma unroll
            for (int i = 0; i < 4; i++) {
                float v = acc[mi][ni][i] + bv[ni];
                if (do_relu) v = fmaxf(v, 0.f);
                cw[(q * 4 + i) * 72 + ni * 16 + r] = (short)f2bf(v);
            }
        int row = lane >> 2, seg = lane & 3;
        int gm = m0 + mi * 16 + row;
        if (gm < M) {
            v8s p0 = *(const v8s*)&cw[row * 72 + seg * 16];
            v8s p1 = *(const v8s*)&cw[row * 72 + seg * 16 + 8];
            size_t o = (size_t)gm * HDIM + w * 64 + seg * 16;
            *(v8s*)&C[o]     = p0;
            *(v8s*)&C[o + 8] = p1;
        }
    }
}

// ================= fused GIN MLP: C = relu(relu(A@W1+b1)@W2+b2) =============
// 64-row block, 4 waves. Both phases barrier-free (B streamed from L2-hot
// Wt with prefetch); Y bounces through 32KB LDS. 2 barriers per block.
__global__ __launch_bounds__(256, 3) void mlp_fused(
    const unsigned short* __restrict__ A,
    const unsigned short* __restrict__ W1t, const float* __restrict__ b1,
    const unsigned short* __restrict__ W2t, const float* __restrict__ b2,
    unsigned short* __restrict__ C, int M)
{
    __shared__ short Ybuf[16384];    // 32KB: 8 k-chunks x 256 slots x 8 shorts
    const int tid = threadIdx.x;
    const int w = tid >> 6, lane = tid & 63;
    const int q = lane >> 4, r = lane & 15;
    const int m0 = blockIdx.x * 64;

    int grow[4];
#pragma unroll
    for (int mi = 0; mi < 4; mi++) {
        int gr = m0 + mi * 16 + r; if (gr >= M) gr = M - 1;
        grow[mi] = gr;
    }
    const size_t bcol = (size_t)(w * 64 + r);   // B row base for this lane

    // ---- phase 1: Y = relu(A @ W1 + b1), barrier-free ----
    v8s af[4], bf[4], afn[4], bfn[4];
#pragma unroll
    for (int mi = 0; mi < 4; mi++)
        af[mi] = *(const v8s*)&A[(size_t)grow[mi] * HDIM + q * 8];
#pragma unroll
    for (int ni = 0; ni < 4; ni++)
        bf[ni] = *(const v8s*)&W1t[(bcol + ni * 16) * HDIM + q * 8];

    v4f acc[4][4];
#pragma unroll
    for (int i = 0; i < 4; i++)
#pragma unroll
        for (int j = 0; j < 4; j++)
            acc[i][j] = (v4f){0.f, 0.f, 0.f, 0.f};

#pragma unroll
    for (int kc = 0; kc < 8; kc++) {
        if (kc < 7) {
            int ko = (kc + 1) * 32 + q * 8;
#pragma unroll
            for (int mi = 0; mi < 4; mi++)
                afn[mi] = *(const v8s*)&A[(size_t)grow[mi] * HDIM + ko];
#pragma unroll
            for (int ni = 0; ni < 4; ni++)
                bfn[ni] = *(const v8s*)&W1t[(bcol + ni * 16) * HDIM + ko];
        } else {
            // prefetch W2 chunk 0 for phase 2 across the barrier
#pragma unroll
            for (int ni = 0; ni < 4; ni++)
                bfn[ni] = *(const v8s*)&W2t[(bcol + ni * 16) * HDIM + q * 8];
        }
#pragma unroll
        for (int mi = 0; mi < 4; mi++)
#pragma unroll
            for (int ni = 0; ni < 4; ni++)
                acc[mi][ni] = __builtin_amdgcn_mfma_f32_16x16x32_bf16(
                    af[mi], bf[ni], acc[mi][ni], 0, 0, 0);
#pragma unroll
        for (int mi = 0; mi < 4; mi++) af[mi] = afn[mi];
#pragma unroll
        for (int ni = 0; ni < 4; ni++) bf[ni] = bfn[ni];
    }

    // Y -> LDS (bias + relu), swizzled chunk-slot layout
    {
        float bv1[4];
#pragma unroll
        for (int ni = 0; ni < 4; ni++)
            bv1[ni] = b1[w * 64 + ni * 16 + r];
#pragma unroll
        for (int mi = 0; mi < 4; mi++)
#pragma unroll
            for (int ni = 0; ni < 4; ni++)
#pragma unroll
                for (int i = 0; i < 4; i++) {
                    float v = fmaxf(acc[mi][ni][i] + bv1[ni], 0.f);
                    int row = mi * 16 + q * 4 + i;
                    int col = w * 64 + ni * 16 + r;
                    int chunk = col >> 5, kk = col & 31;
                    int ko = kk >> 3, j = kk & 7;
                    int slot = row * 4 + ((ko + (row >> 1)) & 3);
                    Ybuf[chunk * 2048 + slot * 8 + j] = (short)f2bf(v);
                }
    }
    __syncthreads();   // barrier 1: Y visible

    // ---- phase 2: C = relu(Y @ W2 + b2); A from LDS, B prefetched ----
    v4f acc2[4][4];
#pragma unroll
    for (int i = 0; i < 4; i++)
#pragma unroll
        for (int j = 0; j < 4; j++)
            acc2[i][j] = (v4f){0.f, 0.f, 0.f, 0.f};

#pragma unroll
    for (int kc = 0; kc < 8; kc++) {
        if (kc < 7) {
            int ko = (kc + 1) * 32 + q * 8;
#pragma unroll
            for (int ni = 0; ni < 4; ni++)
                bfn[ni] = *(const v8s*)&W2t[(bcol + ni * 16) * HDIM + ko];
        }
        v8s af2[4];
#pragma unroll
        for (int mi = 0; mi < 4; mi++) {
            int row = mi * 16 + r;
            int slot = row * 4 + ((q + (row >> 1)) & 3);
            af2[mi] = *(const v8s*)&Ybuf[kc * 2048 + slot * 8];
        }
#pragma unroll
        for (int mi = 0; mi < 4; mi++)
#pragma unroll
            for (int ni = 0; ni < 4; ni++)
                acc2[mi][ni] = __builtin_amdgcn_mfma_f32_16x16x32_bf16(
                    af2[mi], bf[ni], acc2[mi][ni], 0, 0, 0);
#pragma unroll
        for (int ni = 0; ni < 4; ni++) bf[ni] = bfn[ni];
    }
    __syncthreads();   // barrier 2: Ybuf reads done -> reuse for epilogue

    float bv2[4];
#pragma unroll
    for (int ni = 0; ni < 4; ni++)
        bv2[ni] = b2[w * 64 + ni * 16 + r];
#pragma unroll
    for (int mi = 0; mi < 4; mi++) {
        short* cw = &Ybuf[w * 2304 + (mi & 1) * 1152];
#pragma unroll
        for (int ni = 0; ni < 4; ni++)
#pragma unroll
            for (int i = 0; i < 4; i++) {
                float v = fmaxf(acc2[mi][ni][i] + bv2[ni], 0.f);
                cw[(q * 4 + i) * 72 + ni * 16 + r] = (short)f2bf(v);
            }
        int row = lane >> 2, seg = lane & 3;
        int gm = m0 + mi * 16 + row;
        if (gm < M) {
            v8s p0 = *(const v8s*)&cw[row * 72 + seg * 16];
            v8s p1 = *(const v8s*)&cw[row * 72 + seg * 16 + 8];
            size_t o = (size_t)gm * HDIM + w * 64 + seg * 16;
            *(v8s*)&C[o]     = p0;
            *(v8s*)&C[o + 8] = p1;
        }
    }
}

// ================= head GEMM (fp32, M=5000) =================
__global__ __launch_bounds__(256) void gemm_head(
    const float* __restrict__ A, const float* __restrict__ B,
    const float* __restrict__ bias, float* __restrict__ C, int M)
{
    __shared__ float As[16][132];
    __shared__ float Bs[16][132];
    const int tid = threadIdx.x;
    const int tx = tid & 15, ty = tid >> 4;
    const int m0 = blockIdx.x * 128, n0 = blockIdx.y * 128;
    const int arow = tid >> 1, acs = (tid & 1) * 8;
    int gr = m0 + arow; if (gr >= M) gr = M - 1;
    float acc[8][8] = {};

    for (int kt = 0; kt < HDIM; kt += 16) {
        float f[8];
        *(float4*)&f[0] = *(const float4*)&A[(size_t)gr * HDIM + kt + acs];
        *(float4*)&f[4] = *(const float4*)&A[(size_t)gr * HDIM + kt + acs + 4];
#pragma unroll
        for (int j = 0; j < 8; j++) As[acs + j][arow] = f[j];
#pragma unroll
        for (int i = 0; i < 2; i++) {
            int lid = tid * 2 + i;
            int kr = lid >> 5, ns = (lid & 31) * 4;
            *(float4*)&Bs[kr][ns] =
                *(const float4*)&B[(size_t)(kt + kr) * HDIM + n0 + ns];
        }
        __syncthreads();
#pragma unroll
        for (int kl = 0; kl < 16; kl++) {
            float a[8], b[8];
            *(float4*)&a[0] = *(const float4*)&As[kl][ty * 8];
            *(float4*)&a[4] = *(const float4*)&As[kl][ty * 8 + 4];
            *(float4*)&b[0] = *(const float4*)&Bs[kl][tx * 8];
            *(float4*)&b[4] = *(const float4*)&Bs[kl][tx * 8 + 4];
#pragma unroll
            for (int i = 0; i < 8; i++)
#pragma unroll
                for (int j = 0; j < 8; j++)
                    acc[i][j] = fmaf(a[i], b[j], acc[i][j]);
        }
        __syncthreads();
    }

    float bv[8];
    *(float4*)&bv[0] = *(const float4*)&bias[n0 + tx * 8];
    *(float4*)&bv[4] = *(const float4*)&bias[n0 + tx * 8 + 4];
#pragma unroll
    for (int i = 0; i < 8; i++) {
        int gr2 = m0 + ty * 8 + i;
        if (gr2 >= M) break;
        float o[8];
#pragma unroll
        for (int j = 0; j < 8; j++) o[j] = acc[i][j] + bv[j];
        *(float4*)&C[(size_t)gr2 * HDIM + n0 + tx * 8]     = *(float4*)&o[0];
        *(float4*)&C[(size_t)gr2 * HDIM + n0 + tx * 8 + 4] = *(float4*)&o[4];
    }
}

// ================= pooling =================
__global__ __launch_bounds__(256) void bounds_kernel(
    const int* __restrict__ batch, int* __restrict__ gstart, int n, int ngraphs)
{
    int i = blockIdx.x * 256 + threadIdx.x;
    if (i >= n) return;
    int b1 = batch[i];
    int b0 = (i == 0) ? -1 : batch[i - 1];
    for (int g = b0 + 1; g <= b1; g++) gstart[g] = i;
    if (i == n - 1)
        for (int g = b1 + 1; g <= ngraphs; g++) gstart[g] = n;
}

__global__ __launch_bounds__(256) void pool_kernel(
    const unsigned short* __restrict__ h, const int* __restrict__ gstart,
    float* __restrict__ pooled, int ngraphs)
{
    int g = blockIdx.x * 4 + (threadIdx.x >> 6);
    if (g >= ngraphs) return;
    int lane = threadIdx.x & 63;
    int beg = gstart[g], end = gstart[g + 1];
    float a0 = 0.f, a1 = 0.f, a2 = 0.f, a3 = 0.f;
    for (int i = beg; i < end; i++) {
        uint2 r = *(const uint2*)&h[(size_t)i * HDIM + lane * 4];
        a0 += bflo(r.x); a1 += bfhi(r.x); a2 += bflo(r.y); a3 += bfhi(r.y);
    }
    float inv = 1.0f / fmaxf((float)(end - beg), 1.0f);
    float4 o = { a0 * inv, a1 * inv, a2 * inv, a3 * inv };
    *(float4*)&pooled[(size_t)g * HDIM + lane * 4] = o;
}

__global__ __launch_bounds__(256) void head2_kernel(
    const float* __restrict__ hh, const float* __restrict__ w2,
    const float* __restrict__ b2, float* __restrict__ out, int n_graphs)
{
    int g = blockIdx.x * 4 + (threadIdx.x >> 6);
    int lane = threadIdx.x & 63;
    float p = 0.f;
    if (g < n_graphs) {
        float4 v = *(const float4*)&hh[(size_t)g * HDIM + lane * 4];
        float4 w = *(const float4*)&w2[lane * 4];
        p = v.x * w.x + v.y * w.y + v.z * w.z + v.w * w.w;
    }
#pragma unroll
    for (int off = 32; off > 0; off >>= 1) p += __shfl_down(p, off, 64);
    if (g < n_graphs && lane == 0) out[g] = p + b2[0];
}

extern "C" void kernel_launch(void* const* d_in, const int* in_sizes, int n_in,
                              void* d_out, int out_size, void* d_ws, size_t ws_size,
                              hipStream_t stream)
{
    const float* x    = (const float*)d_in[0];
    const int*   ei   = (const int*)d_in[1];
    const int*   batch= (const int*)d_in[2];
    const float* g0w1 = (const float*)d_in[3];
    const float* g0b1 = (const float*)d_in[4];
    const float* g0w2 = (const float*)d_in[5];
    const float* g0b2 = (const float*)d_in[6];
    const float* gw1  = (const float*)d_in[7];
    const float* gb1  = (const float*)d_in[8];
    const float* gw2  = (const float*)d_in[9];
    const float* gb2  = (const float*)d_in[10];
    const float* hw1  = (const float*)d_in[11];
    const float* hb1  = (const float*)d_in[12];
    const float* hw2  = (const float*)d_in[13];
    const float* hb2  = (const float*)d_in[14];

    const int n_nodes  = in_sizes[0] / 11;
    const int n_edges  = in_sizes[1] / 2;
    const int n_graphs = out_size;

    const int* srcp = ei;
    const int* dstp = ei + n_edges;

    // ---- workspace carve-up (bytes) ----
    const size_t NF = (size_t)n_nodes * HDIM;
    char* p = (char*)d_ws;
    unsigned short* H0 = (unsigned short*)p; p += NF * 2;
    unsigned short* H1 = (unsigned short*)p; p += NF * 2;
    unsigned short* Bts = (unsigned short*)p; p += (size_t)9 * 65536 * 2;
    float* xsum    = (float*)p; p += (size_t)n_nodes * 11 * 4;
    float* pooled  = (float*)p; p += (size_t)n_graphs * HDIM * 4;
    float* hh      = (float*)p; p += (size_t)n_graphs * HDIM * 4;
    int* deg       = (int*)p; p += (size_t)n_nodes * 4;
    int* scanex    = (int*)p; p += (size_t)n_nodes * 4;
    int* partials  = (int*)p; p += 512 * 4;
    int* rowptr    = (int*)p; p += ((size_t)n_nodes + 1) * 4;
    int* cursor    = (int*)p; p += (size_t)n_nodes * 4;
    int* csr_src   = (int*)p; p += (size_t)n_edges * 4;
    int* gstart    = (int*)p; p += ((size_t)n_graphs + 1) * 4;
    if ((size_t)(p - (char*)d_ws) > ws_size) return;

    const int nblk = (n_nodes + 255) / 256;

    // ---- weight convert ----
    convw_kernel<<<(9 * 65536 + 255) / 256, 256, 0, stream>>>(g0w2, gw1, gw2, Bts);

    // ---- CSR build ----
    hipMemsetAsync(deg, 0, (size_t)n_nodes * 4, stream);
    hist_kernel<<<(n_edges + 255) / 256, 256, 0, stream>>>(dstp, deg, n_edges);
    scan1_kernel<<<nblk, 256, 0, stream>>>(deg, scanex, partials, n_nodes);
    scan2_kernel<<<1, 512, 0, stream>>>(partials, nblk);
    scan3_kernel<<<nblk, 256, 0, stream>>>(scanex, partials, rowptr, cursor,
                                           n_nodes, n_edges);
    fill_kernel<<<(n_edges + 255) / 256, 256, 0, stream>>>(
        srcp, dstp, cursor, csr_src, n_edges);

    bounds_kernel<<<nblk, 256, 0, stream>>>(batch, gstart, n_nodes, n_graphs);

    const int tileGrid = (n_nodes + 63) / 64;

    // ---- gin0 (IN=11) ----
    agg0_kernel<<<((size_t)n_nodes * 16 + 255) / 256, 256, 0, stream>>>(
        x, rowptr, csr_src, xsum, n_nodes);
    gemm0_kernel<<<(n_nodes + 3) / 4, 256, 0, stream>>>(xsum, g0w1, g0b1, H1, n_nodes);
    gemm_one<<<tileGrid, 256, 0, stream>>>(H1, Bts + 0, g0b2, H0, n_nodes, 1);

    // ---- 4 GIN layers: agg(cur->t), fused MLP(t)->cur ----
    unsigned short* cur = H0;
    unsigned short* t   = H1;
    const int aggGrid = (n_nodes + 7) / 8;
    for (int l = 0; l < 4; l++) {
        agg_bf_kernel<<<aggGrid, 256, 0, stream>>>(cur, rowptr, csr_src, t, n_nodes);
        mlp_fused<<<tileGrid, 256, 0, stream>>>(
            t, Bts + (size_t)(1 + l) * 65536, gb1 + (size_t)l * HDIM,
            Bts + (size_t)(5 + l) * 65536, gb2 + (size_t)l * HDIM,
            cur, n_nodes);
    }

    // ---- mean pool ----
    pool_kernel<<<(n_graphs + 3) / 4, 256, 0, stream>>>(cur, gstart, pooled, n_graphs);

    // ---- head ----
    gemm_head<<<dim3((n_graphs + 127) / 128, 2), 256, 0, stream>>>(
        pooled, hw1, hb1, hh, n_graphs);
    head2_kernel<<<(n_graphs + 3) / 4, 256, 0, stream>>>(
        hh, hw2, hb2, (float*)d_out, n_graphs);
}

// Round 11
// 704.382 us; speedup vs baseline: 1.1781x; 1.1781x over previous
//
#include <hip/hip_runtime.h>
#include <hip/hip_bf16.h>

// GIN forward, round 11: R9's vmcnt(N) race confirmed (global_load_lds->ds_read
// cannot be guarded by partial vmcnt on gfx950; absmax 3.56). Revert W staging
// to the proven R5 block-cooperative pattern (2 barriers/chunk), KEEP the agg
// fusion: each block gathers h+sum_nbr for its 64 rows straight into the
// swizzled LDS A-layout (no global t buffer, no separate agg dispatch).

constexpr int HDIM = 256;

typedef short v8s __attribute__((ext_vector_type(8)));
typedef float v4f __attribute__((ext_vector_type(4)));

__device__ __forceinline__ float bflo(unsigned int u) { return __uint_as_float(u << 16); }
__device__ __forceinline__ float bfhi(unsigned int u) { return __uint_as_float(u & 0xffff0000u); }
__device__ __forceinline__ unsigned short f2bf(float f) {
    unsigned int u = __float_as_uint(f);
    return (unsigned short)((u + 0x7fffu + ((u >> 16) & 1u)) >> 16);  // RNE
}

__device__ __forceinline__ void gload16(const void* g, void* l) {
    __builtin_amdgcn_global_load_lds(
        (const __attribute__((address_space(1))) unsigned int*)g,
        (__attribute__((address_space(3))) unsigned int*)l, 16, 0, 0);
}

// ================= CSR build =================
__global__ __launch_bounds__(256) void hist_kernel(
    const int* __restrict__ dst, int* __restrict__ deg, int n_edges)
{
    int e = blockIdx.x * 256 + threadIdx.x;
    if (e < n_edges) atomicAdd(&deg[dst[e]], 1);
}

__global__ __launch_bounds__(256) void scan1_kernel(
    const int* __restrict__ deg, int* __restrict__ scanex,
    int* __restrict__ partials, int n)
{
    __shared__ int s[256];
    int i = blockIdx.x * 256 + threadIdx.x;
    int v = (i < n) ? deg[i] : 0;
    s[threadIdx.x] = v;
    __syncthreads();
#pragma unroll
    for (int off = 1; off < 256; off <<= 1) {
        int t = (threadIdx.x >= off) ? s[threadIdx.x - off] : 0;
        __syncthreads();
        s[threadIdx.x] += t;
        __syncthreads();
    }
    if (i < n) scanex[i] = s[threadIdx.x] - v;
    if (threadIdx.x == 255) partials[blockIdx.x] = s[255];
}

__global__ __launch_bounds__(512) void scan2_kernel(int* __restrict__ partials, int nb)
{
    __shared__ int s[512];
    int v = (threadIdx.x < nb) ? partials[threadIdx.x] : 0;
    s[threadIdx.x] = v;
    __syncthreads();
#pragma unroll
    for (int off = 1; off < 512; off <<= 1) {
        int t = (threadIdx.x >= off) ? s[threadIdx.x - off] : 0;
        __syncthreads();
        s[threadIdx.x] += t;
        __syncthreads();
    }
    if (threadIdx.x < nb) partials[threadIdx.x] = s[threadIdx.x] - v;
}

__global__ __launch_bounds__(256) void scan3_kernel(
    const int* __restrict__ scanex, const int* __restrict__ partials,
    int* __restrict__ rowptr, int* __restrict__ cursor, int n, int n_edges)
{
    int i = blockIdx.x * 256 + threadIdx.x;
    if (i < n) {
        int v = scanex[i] + partials[blockIdx.x];
        rowptr[i] = v;
        cursor[i] = v;
    }
    if (i == 0) rowptr[n] = n_edges;
}

__global__ __launch_bounds__(256) void fill_kernel(
    const int* __restrict__ src, const int* __restrict__ dst,
    int* __restrict__ cursor, int* __restrict__ csr_src, int n_edges)
{
    int e = blockIdx.x * 256 + threadIdx.x;
    if (e >= n_edges) return;
    int slot = atomicAdd(&cursor[dst[e]], 1);
    csr_src[slot] = src[e];
}

// ================= weight convert: Wt[n][k] = bf16(W[k][n]) =================
__global__ __launch_bounds__(256) void convw_kernel(
    const float* __restrict__ g0w2, const float* __restrict__ gw1,
    const float* __restrict__ gw2, unsigned short* __restrict__ Bts)
{
    int gid = blockIdx.x * 256 + threadIdx.x;
    if (gid >= 9 * 65536) return;
    int m = gid >> 16;
    int e = gid & 0xffff;
    int n = e >> 8, k = e & 255;
    const float* W = (m == 0) ? g0w2
                   : (m <= 4) ? gw1 + (size_t)(m - 1) * 65536
                              : gw2 + (size_t)(m - 5) * 65536;
    Bts[(size_t)m * 65536 + n * 256 + k] = f2bf(W[k * 256 + n]);
}

// ================= layer-0 (K=11) =================
__global__ __launch_bounds__(256) void agg0_kernel(
    const float* __restrict__ x, const int* __restrict__ rowptr,
    const int* __restrict__ csr_src, float* __restrict__ xsum, int n)
{
    int gid = blockIdx.x * 256 + threadIdx.x;
    int node = gid >> 4, f = gid & 15;
    if (node >= n || f >= 11) return;
    float acc = x[(size_t)node * 11 + f];
    int beg = rowptr[node], end = rowptr[node + 1];
    for (int e = beg; e < end; e++)
        acc += x[(size_t)csr_src[e] * 11 + f];
    xsum[(size_t)node * 11 + f] = acc;
}

__global__ __launch_bounds__(256) void gemm0_kernel(
    const float* __restrict__ xsum, const float* __restrict__ w1,
    const float* __restrict__ b1, unsigned short* __restrict__ out, int M)
{
    int row = blockIdx.x * 4 + (threadIdx.x >> 6);
    if (row >= M) return;
    int lane = threadIdx.x & 63;
    float xr[11];
#pragma unroll
    for (int k = 0; k < 11; k++) xr[k] = xsum[(size_t)row * 11 + k];
    int n = lane * 4;
    float4 acc = *(const float4*)&b1[n];
#pragma unroll
    for (int k = 0; k < 11; k++) {
        float4 w = *(const float4*)&w1[k * HDIM + n];
        acc.x = fmaf(xr[k], w.x, acc.x);
        acc.y = fmaf(xr[k], w.y, acc.y);
        acc.z = fmaf(xr[k], w.z, acc.z);
        acc.w = fmaf(xr[k], w.w, acc.w);
    }
    uint2 o;
    o.x = (unsigned int)f2bf(fmaxf(acc.x, 0.f)) | ((unsigned int)f2bf(fmaxf(acc.y, 0.f)) << 16);
    o.y = (unsigned int)f2bf(fmaxf(acc.z, 0.f)) | ((unsigned int)f2bf(fmaxf(acc.w, 0.f)) << 16);
    *(uint2*)&out[(size_t)row * HDIM + n] = o;
}

// ================= single MFMA GEMM (layer-0 second linear) =================
// R4/R5-proven 128x128 tile, BK=32, 4 waves, global_load_lds + barriers.
__global__ __launch_bounds__(256) void gemm_mfma(
    const unsigned short* __restrict__ A, const unsigned short* __restrict__ Wt,
    const float* __restrict__ bias, unsigned short* __restrict__ C,
    int M, int do_relu)
{
    __shared__ short lds[2][512 * 8];
    const int tid = threadIdx.x;
    const int w = tid >> 6, lane = tid & 63;
    const int q = lane >> 4, r = lane & 15;
    const int rh = w & 1, ch = w >> 1;
    const int m0 = blockIdx.x * 128, n0 = blockIdx.y * 128;

    v4f acc[4][4];
#pragma unroll
    for (int i = 0; i < 4; i++)
#pragma unroll
        for (int j = 0; j < 4; j++)
            acc[i][j] = (v4f){0.f, 0.f, 0.f, 0.f};

    for (int kt = 0; kt < HDIM; kt += 32) {
#pragma unroll
        for (int rd = 0; rd < 2; rd++) {
            int cb = rd * 256 + w * 64;
            int s  = cb + lane;
            int row = s >> 2;
            int ko  = ((s & 3) - (row >> 1)) & 3;
            int gr = m0 + row; if (gr >= M) gr = M - 1;
            gload16(&A[(size_t)gr * HDIM + kt + ko * 8],  &lds[0][cb * 8]);
            gload16(&Wt[(size_t)(n0 + row) * HDIM + kt + ko * 8], &lds[1][cb * 8]);
        }
        __syncthreads();
        v8s af[4], bf[4];
#pragma unroll
        for (int mi = 0; mi < 4; mi++) {
            int row = rh * 64 + mi * 16 + r;
            int slot = row * 4 + ((q + (row >> 1)) & 3);
            af[mi] = *(const v8s*)&lds[0][slot * 8];
        }
#pragma unroll
        for (int ni = 0; ni < 4; ni++) {
            int row = ch * 64 + ni * 16 + r;
            int slot = row * 4 + ((q + (row >> 1)) & 3);
            bf[ni] = *(const v8s*)&lds[1][slot * 8];
        }
#pragma unroll
        for (int mi = 0; mi < 4; mi++)
#pragma unroll
            for (int ni = 0; ni < 4; ni++)
                acc[mi][ni] = __builtin_amdgcn_mfma_f32_16x16x32_bf16(
                    af[mi], bf[ni], acc[mi][ni], 0, 0, 0);
        __syncthreads();
    }

    float bv[4];
#pragma unroll
    for (int ni = 0; ni < 4; ni++)
        bv[ni] = bias[n0 + ch * 64 + ni * 16 + r];

    short* cw = &lds[0][0] + w * (16 * 72);
#pragma unroll
    for (int mi = 0; mi < 4; mi++) {
#pragma unroll
        for (int ni = 0; ni < 4; ni++)
#pragma unroll
            for (int i = 0; i < 4; i++) {
                float v = acc[mi][ni][i] + bv[ni];
                if (do_relu) v = fmaxf(v, 0.f);
                cw[(q * 4 + i) * 72 + ni * 16 + r] = (short)f2bf(v);
            }
        __syncthreads();
        int row = lane >> 2, seg = lane & 3;
        int gm = m0 + rh * 64 + mi * 16 + row;
        if (gm < M) {
            v8s p0 = *(const v8s*)&cw[row * 72 + seg * 16];
            v8s p1 = *(const v8s*)&cw[row * 72 + seg * 16 + 8];
            size_t o = (size_t)gm * HDIM + n0 + ch * 64 + seg * 16;
            *(v8s*)&C[o]     = p0;
            *(v8s*)&C[o + 8] = p1;
        }
        __syncthreads();
    }
}

// ================= fused GIN layer: C = MLP(h + sum_nbr h) ==================
// 64-row block, 4 waves. Agg gathered straight into swizzled LDS A-layout;
// W staged per 32-k chunk block-cooperatively (R5 pattern, 2 barriers/chunk).
__global__ __launch_bounds__(256, 3) void gin_layer(
    const unsigned short* __restrict__ h,
    const int* __restrict__ rowptr, const int* __restrict__ csr_src,
    const unsigned short* __restrict__ W1t, const float* __restrict__ b1,
    const unsigned short* __restrict__ W2t, const float* __restrict__ b2,
    unsigned short* __restrict__ C, int M)
{
    __shared__ short AY[16384];      // 32KB: A, then Y, then epilogue bounce
    __shared__ short Wstage[8192];   // 16KB: current W chunk (256 cols x 32k)
    const int tid = threadIdx.x;
    const int w = tid >> 6, lane = tid & 63;
    const int q = lane >> 4, r = lane & 15;
    const int hw = tid >> 5, l = tid & 31;
    const int m0 = blockIdx.x * 64;

    // ---- aggregation: AY = h[node] + sum_nbr h[src], swizzled A layout ----
    for (int it = 0; it < 8; it++) {
        int row = it * 8 + hw;
        int node = m0 + row; if (node >= M) node = M - 1;
        uint4 raw = *(const uint4*)&h[(size_t)node * HDIM + l * 8];
        float a0 = bflo(raw.x), a1 = bfhi(raw.x), a2 = bflo(raw.y), a3 = bfhi(raw.y);
        float a4 = bflo(raw.z), a5 = bfhi(raw.z), a6 = bflo(raw.w), a7 = bfhi(raw.w);
        int beg = rowptr[node], end = rowptr[node + 1];
        int e = beg;
        for (; e + 1 < end; e += 2) {
            int s0 = csr_src[e], s1 = csr_src[e + 1];
            uint4 r0 = *(const uint4*)&h[(size_t)s0 * HDIM + l * 8];
            uint4 r1 = *(const uint4*)&h[(size_t)s1 * HDIM + l * 8];
            a0 += bflo(r0.x); a1 += bfhi(r0.x); a2 += bflo(r0.y); a3 += bfhi(r0.y);
            a4 += bflo(r0.z); a5 += bfhi(r0.z); a6 += bflo(r0.w); a7 += bfhi(r0.w);
            a0 += bflo(r1.x); a1 += bfhi(r1.x); a2 += bflo(r1.y); a3 += bfhi(r1.y);
            a4 += bflo(r1.z); a5 += bfhi(r1.z); a6 += bflo(r1.w); a7 += bfhi(r1.w);
        }
        if (e < end) {
            int s0 = csr_src[e];
            uint4 r0 = *(const uint4*)&h[(size_t)s0 * HDIM + l * 8];
            a0 += bflo(r0.x); a1 += bfhi(r0.x); a2 += bflo(r0.y); a3 += bfhi(r0.y);
            a4 += bflo(r0.z); a5 += bfhi(r0.z); a6 += bflo(r0.w); a7 += bfhi(r0.w);
        }
        uint4 o;
        o.x = (unsigned int)f2bf(a0) | ((unsigned int)f2bf(a1) << 16);
        o.y = (unsigned int)f2bf(a2) | ((unsigned int)f2bf(a3) << 16);
        o.z = (unsigned int)f2bf(a4) | ((unsigned int)f2bf(a5) << 16);
        o.w = (unsigned int)f2bf(a6) | ((unsigned int)f2bf(a7) << 16);
        // cols l*8..l*8+7 -> chunk = l>>2, ko = l&3
        int slot = row * 4 + (((l & 3) + (row >> 1)) & 3);
        *(uint4*)&AY[(l >> 2) * 2048 + slot * 8] = o;
    }

    // ---- phase 1: Y = relu(A @ W1 + b1) ----
    v4f acc[4][4];
#pragma unroll
    for (int i = 0; i < 4; i++)
#pragma unroll
        for (int j = 0; j < 4; j++)
            acc[i][j] = (v4f){0.f, 0.f, 0.f, 0.f};

    for (int kc = 0; kc < 8; kc++) {
#pragma unroll
        for (int rd = 0; rd < 4; rd++) {   // stage W1 chunk kc: 1024 slots
            int cb = rd * 256 + w * 64;
            int s = cb + lane;
            int n = s >> 2;
            int ko = ((s & 3) - (n >> 1)) & 3;
            gload16(&W1t[(size_t)n * HDIM + kc * 32 + ko * 8], &Wstage[cb * 8]);
        }
        __syncthreads();   // agg (kc=0) + W chunk visible
        v8s af[4], bf[4];
#pragma unroll
        for (int mi = 0; mi < 4; mi++) {
            int row = mi * 16 + r;
            int slot = row * 4 + ((q + (row >> 1)) & 3);
            af[mi] = *(const v8s*)&AY[kc * 2048 + slot * 8];
        }
#pragma unroll
        for (int ni = 0; ni < 4; ni++) {
            int n = w * 64 + ni * 16 + r;
            int slot = n * 4 + ((q + (n >> 1)) & 3);
            bf[ni] = *(const v8s*)&Wstage[slot * 8];
        }
#pragma unroll
        for (int mi = 0; mi < 4; mi++)
#pragma unroll
            for (int ni = 0; ni < 4; ni++)
                acc[mi][ni] = __builtin_amdgcn_mfma_f32_16x16x32_bf16(
                    af[mi], bf[ni], acc[mi][ni], 0, 0, 0);
        __syncthreads();   // all reads done before next stage overwrites
    }

    // Y -> AY (bias + relu), same swizzled layout
    {
        float bv1[4];
#pragma unroll
        for (int ni = 0; ni < 4; ni++)
            bv1[ni] = b1[w * 64 + ni * 16 + r];
#pragma unroll
        for (int mi = 0; mi < 4; mi++)
#pragma unroll
            for (int ni = 0; ni < 4; ni++)
#pragma unroll
                for (int i = 0; i < 4; i++) {
                    float v = fmaxf(acc[mi][ni][i] + bv1[ni], 0.f);
                    int row = mi * 16 + q * 4 + i;
                    int col = w * 64 + ni * 16 + r;
                    int chunk = col >> 5, kk = col & 31;
                    int ko = kk >> 3, j = kk & 7;
                    int slot = row * 4 + ((ko + (row >> 1)) & 3);
                    AY[chunk * 2048 + slot * 8 + j] = (short)f2bf(v);
                }
    }
    __syncthreads();   // Y visible

    // ---- phase 2: C = relu(Y @ W2 + b2) ----
    v4f acc2[4][4];
#pragma unroll
    for (int i = 0; i < 4; i++)
#pragma unroll
        for (int j = 0; j < 4; j++)
            acc2[i][j] = (v4f){0.f, 0.f, 0.f, 0.f};

    for (int kc = 0; kc < 8; kc++) {
#pragma unroll
        for (int rd = 0; rd < 4; rd++) {   // stage W2 chunk kc
            int cb = rd * 256 + w * 64;
            int s = cb + lane;
            int n = s >> 2;
            int ko = ((s & 3) - (n >> 1)) & 3;
            gload16(&W2t[(size_t)n * HDIM + kc * 32 + ko * 8], &Wstage[cb * 8]);
        }
        __syncthreads();
        v8s af[4], bf[4];
#pragma unroll
        for (int mi = 0; mi < 4; mi++) {
            int row = mi * 16 + r;
            int slot = row * 4 + ((q + (row >> 1)) & 3);
            af[mi] = *(const v8s*)&AY[kc * 2048 + slot * 8];
        }
#pragma unroll
        for (int ni = 0; ni < 4; ni++) {
            int n = w * 64 + ni * 16 + r;
            int slot = n * 4 + ((q + (n >> 1)) & 3);
            bf[ni] = *(const v8s*)&Wstage[slot * 8];
        }
#pragma unroll
        for (int mi = 0; mi < 4; mi++)
#pragma unroll
            for (int ni = 0; ni < 4; ni++)
                acc2[mi][ni] = __builtin_amdgcn_mfma_f32_16x16x32_bf16(
                    af[mi], bf[ni], acc2[mi][ni], 0, 0, 0);
        __syncthreads();   // Y/W reads done (last iter: AY free for epilogue)
    }

    // epilogue: per-wave LDS bounce (reuse AY), coalesced bf16 stores
    float bv2[4];
#pragma unroll
    for (int ni = 0; ni < 4; ni++)
        bv2[ni] = b2[w * 64 + ni * 16 + r];
#pragma unroll
    for (int mi = 0; mi < 4; mi++) {
        short* cw = &AY[w * 2304 + (mi & 1) * 1152];
#pragma unroll
        for (int ni = 0; ni < 4; ni++)
#pragma unroll
            for (int i = 0; i < 4; i++) {
                float v = fmaxf(acc2[mi][ni][i] + bv2[ni], 0.f);
                cw[(q * 4 + i) * 72 + ni * 16 + r] = (short)f2bf(v);
            }
        int row = lane >> 2, seg = lane & 3;
        int gm = m0 + mi * 16 + row;
        if (gm < M) {
            v8s p0 = *(const v8s*)&cw[row * 72 + seg * 16];
            v8s p1 = *(const v8s*)&cw[row * 72 + seg * 16 + 8];
            size_t o = (size_t)gm * HDIM + w * 64 + seg * 16;
            *(v8s*)&C[o]     = p0;
            *(v8s*)&C[o + 8] = p1;
        }
    }
}

// ================= head GEMM (fp32, M=5000) =================
__global__ __launch_bounds__(256) void gemm_head(
    const float* __restrict__ A, const float* __restrict__ B,
    const float* __restrict__ bias, float* __restrict__ C, int M)
{
    __shared__ float As[16][132];
    __shared__ float Bs[16][132];
    const int tid = threadIdx.x;
    const int tx = tid & 15, ty = tid >> 4;
    const int m0 = blockIdx.x * 128, n0 = blockIdx.y * 128;
    const int arow = tid >> 1, acs = (tid & 1) * 8;
    int gr = m0 + arow; if (gr >= M) gr = M - 1;
    float acc[8][8] = {};

    for (int kt = 0; kt < HDIM; kt += 16) {
        float f[8];
        *(float4*)&f[0] = *(const float4*)&A[(size_t)gr * HDIM + kt + acs];
        *(float4*)&f[4] = *(const float4*)&A[(size_t)gr * HDIM + kt + acs + 4];
#pragma unroll
        for (int j = 0; j < 8; j++) As[acs + j][arow] = f[j];
#pragma unroll
        for (int i = 0; i < 2; i++) {
            int lid = tid * 2 + i;
            int kr = lid >> 5, ns = (lid & 31) * 4;
            *(float4*)&Bs[kr][ns] =
                *(const float4*)&B[(size_t)(kt + kr) * HDIM + n0 + ns];
        }
        __syncthreads();
#pragma unroll
        for (int kl = 0; kl < 16; kl++) {
            float a[8], b[8];
            *(float4*)&a[0] = *(const float4*)&As[kl][ty * 8];
            *(float4*)&a[4] = *(const float4*)&As[kl][ty * 8 + 4];
            *(float4*)&b[0] = *(const float4*)&Bs[kl][tx * 8];
            *(float4*)&b[4] = *(const float4*)&Bs[kl][tx * 8 + 4];
#pragma unroll
            for (int i = 0; i < 8; i++)
#pragma unroll
                for (int j = 0; j < 8; j++)
                    acc[i][j] = fmaf(a[i], b[j], acc[i][j]);
        }
        __syncthreads();
    }

    float bv[8];
    *(float4*)&bv[0] = *(const float4*)&bias[n0 + tx * 8];
    *(float4*)&bv[4] = *(const float4*)&bias[n0 + tx * 8 + 4];
#pragma unroll
    for (int i = 0; i < 8; i++) {
        int gr2 = m0 + ty * 8 + i;
        if (gr2 >= M) break;
        float o[8];
#pragma unroll
        for (int j = 0; j < 8; j++) o[j] = acc[i][j] + bv[j];
        *(float4*)&C[(size_t)gr2 * HDIM + n0 + tx * 8]     = *(float4*)&o[0];
        *(float4*)&C[(size_t)gr2 * HDIM + n0 + tx * 8 + 4] = *(float4*)&o[4];
    }
}

// ================= pooling =================
__global__ __launch_bounds__(256) void bounds_kernel(
    const int* __restrict__ batch, int* __restrict__ gstart, int n, int ngraphs)
{
    int i = blockIdx.x * 256 + threadIdx.x;
    if (i >= n) return;
    int b1 = batch[i];
    int b0 = (i == 0) ? -1 : batch[i - 1];
    for (int g = b0 + 1; g <= b1; g++) gstart[g] = i;
    if (i == n - 1)
        for (int g = b1 + 1; g <= ngraphs; g++) gstart[g] = n;
}

__global__ __launch_bounds__(256) void pool_kernel(
    const unsigned short* __restrict__ h, const int* __restrict__ gstart,
    float* __restrict__ pooled, int ngraphs)
{
    int g = blockIdx.x * 4 + (threadIdx.x >> 6);
    if (g >= ngraphs) return;
    int lane = threadIdx.x & 63;
    int beg = gstart[g], end = gstart[g + 1];
    float a0 = 0.f, a1 = 0.f, a2 = 0.f, a3 = 0.f;
    for (int i = beg; i < end; i++) {
        uint2 r = *(const uint2*)&h[(size_t)i * HDIM + lane * 4];
        a0 += bflo(r.x); a1 += bfhi(r.x); a2 += bflo(r.y); a3 += bfhi(r.y);
    }
    float inv = 1.0f / fmaxf((float)(end - beg), 1.0f);
    float4 o = { a0 * inv, a1 * inv, a2 * inv, a3 * inv };
    *(float4*)&pooled[(size_t)g * HDIM + lane * 4] = o;
}

__global__ __launch_bounds__(256) void head2_kernel(
    const float* __restrict__ hh, const float* __restrict__ w2,
    const float* __restrict__ b2, float* __restrict__ out, int n_graphs)
{
    int g = blockIdx.x * 4 + (threadIdx.x >> 6);
    int lane = threadIdx.x & 63;
    float p = 0.f;
    if (g < n_graphs) {
        float4 v = *(const float4*)&hh[(size_t)g * HDIM + lane * 4];
        float4 w = *(const float4*)&w2[lane * 4];
        p = v.x * w.x + v.y * w.y + v.z * w.z + v.w * w.w;
    }
#pragma unroll
    for (int off = 32; off > 0; off >>= 1) p += __shfl_down(p, off, 64);
    if (g < n_graphs && lane == 0) out[g] = p + b2[0];
}

extern "C" void kernel_launch(void* const* d_in, const int* in_sizes, int n_in,
                              void* d_out, int out_size, void* d_ws, size_t ws_size,
                              hipStream_t stream)
{
    const float* x    = (const float*)d_in[0];
    const int*   ei   = (const int*)d_in[1];
    const int*   batch= (const int*)d_in[2];
    const float* g0w1 = (const float*)d_in[3];
    const float* g0b1 = (const float*)d_in[4];
    const float* g0w2 = (const float*)d_in[5];
    const float* g0b2 = (const float*)d_in[6];
    const float* gw1  = (const float*)d_in[7];
    const float* gb1  = (const float*)d_in[8];
    const float* gw2  = (const float*)d_in[9];
    const float* gb2  = (const float*)d_in[10];
    const float* hw1  = (const float*)d_in[11];
    const float* hb1  = (const float*)d_in[12];
    const float* hw2  = (const float*)d_in[13];
    const float* hb2  = (const float*)d_in[14];

    const int n_nodes  = in_sizes[0] / 11;
    const int n_edges  = in_sizes[1] / 2;
    const int n_graphs = out_size;

    const int* srcp = ei;
    const int* dstp = ei + n_edges;

    // ---- workspace carve-up (bytes) ----
    const size_t NF = (size_t)n_nodes * HDIM;
    char* p = (char*)d_ws;
    unsigned short* H0 = (unsigned short*)p; p += NF * 2;
    unsigned short* H1 = (unsigned short*)p; p += NF * 2;
    unsigned short* Bts = (unsigned short*)p; p += (size_t)9 * 65536 * 2;
    float* xsum    = (float*)p; p += (size_t)n_nodes * 11 * 4;
    float* pooled  = (float*)p; p += (size_t)n_graphs * HDIM * 4;
    float* hh      = (float*)p; p += (size_t)n_graphs * HDIM * 4;
    int* deg       = (int*)p; p += (size_t)n_nodes * 4;
    int* scanex    = (int*)p; p += (size_t)n_nodes * 4;
    int* partials  = (int*)p; p += 512 * 4;
    int* rowptr    = (int*)p; p += ((size_t)n_nodes + 1) * 4;
    int* cursor    = (int*)p; p += (size_t)n_nodes * 4;
    int* csr_src   = (int*)p; p += (size_t)n_edges * 4;
    int* gstart    = (int*)p; p += ((size_t)n_graphs + 1) * 4;
    if ((size_t)(p - (char*)d_ws) > ws_size) return;

    const int nblk = (n_nodes + 255) / 256;

    // ---- weight convert ----
    convw_kernel<<<(9 * 65536 + 255) / 256, 256, 0, stream>>>(g0w2, gw1, gw2, Bts);

    // ---- CSR build ----
    hipMemsetAsync(deg, 0, (size_t)n_nodes * 4, stream);
    hist_kernel<<<(n_edges + 255) / 256, 256, 0, stream>>>(dstp, deg, n_edges);
    scan1_kernel<<<nblk, 256, 0, stream>>>(deg, scanex, partials, n_nodes);
    scan2_kernel<<<1, 512, 0, stream>>>(partials, nblk);
    scan3_kernel<<<nblk, 256, 0, stream>>>(scanex, partials, rowptr, cursor,
                                           n_nodes, n_edges);
    fill_kernel<<<(n_edges + 255) / 256, 256, 0, stream>>>(
        srcp, dstp, cursor, csr_src, n_edges);

    bounds_kernel<<<nblk, 256, 0, stream>>>(batch, gstart, n_nodes, n_graphs);

    // ---- gin0 (IN=11) ----
    agg0_kernel<<<((size_t)n_nodes * 16 + 255) / 256, 256, 0, stream>>>(
        x, rowptr, csr_src, xsum, n_nodes);
    gemm0_kernel<<<(n_nodes + 3) / 4, 256, 0, stream>>>(xsum, g0w1, g0b1, H1, n_nodes);
    gemm_mfma<<<dim3((n_nodes + 127) / 128, 2), 256, 0, stream>>>(
        H1, Bts + 0, g0b2, H0, n_nodes, 1);

    // ---- 4 GIN layers: fused agg+MLP, ping-pong H0/H1 ----
    const int tileGrid = (n_nodes + 63) / 64;
    unsigned short* cur = H0;
    unsigned short* oth = H1;
    for (int l = 0; l < 4; l++) {
        gin_layer<<<tileGrid, 256, 0, stream>>>(
            cur, rowptr, csr_src,
            Bts + (size_t)(1 + l) * 65536, gb1 + (size_t)l * HDIM,
            Bts + (size_t)(5 + l) * 65536, gb2 + (size_t)l * HDIM,
            oth, n_nodes);
        unsigned short* t = cur; cur = oth; oth = t;
    }

    // ---- mean pool ----
    pool_kernel<<<(n_graphs + 3) / 4, 256, 0, stream>>>(cur, gstart, pooled, n_graphs);

    // ---- head ----
    gemm_head<<<dim3((n_graphs + 127) / 128, 2), 256, 0, stream>>>(
        pooled, hw1, hb1, hh, n_graphs);
    head2_kernel<<<(n_graphs + 3) / 4, 256, 0, stream>>>(
        hh, hw2, hb2, (float*)d_out, n_graphs);
}